// Round 6
// baseline (80.154 us; speedup 1.0000x reference)
//
#include <hip/hip_runtime.h>
#include <hip/hip_bf16.h>

#define DD 256
#define SS 4096

typedef __bf16 bf16x8 __attribute__((ext_vector_type(8)));
typedef float  f32x4  __attribute__((ext_vector_type(4)));

__device__ __forceinline__ float fast_tanh(float x) {
  float e = __expf(2.0f * x);
  return 1.0f - 2.0f / (e + 1.0f);
}

// DPP helpers: reduce across the 16-lane row (lg = lane&15) within each g-group
template<int CTRL>
__device__ __forceinline__ float dpp_mov(float v) {
  return __int_as_float(__builtin_amdgcn_update_dpp(0, __float_as_int(v), CTRL, 0xF, 0xF, true));
}
__device__ __forceinline__ float row16_sum(float v) {
  v += dpp_mov<0xB1>(v);   // quad_perm xor1
  v += dpp_mov<0x4E>(v);   // quad_perm xor2
  v += dpp_mov<0x124>(v);  // row_ror:4
  v += dpp_mov<0x128>(v);  // row_ror:8
  return v;
}
__device__ __forceinline__ float row16_max(float v) {
  v = fmaxf(v, dpp_mov<0xB1>(v));
  v = fmaxf(v, dpp_mov<0x4E>(v));
  v = fmaxf(v, dpp_mov<0x124>(v));
  v = fmaxf(v, dpp_mov<0x128>(v));
  return v;
}

// Prep: W [256,256] fp32 -> fragment-ordered bf16 WF.
// Chunk c = ((n0*8+ks)*64 + lane) holds 8 bf16: W[ks*32+(lane>>4)*8+i][n0*16+(lane&15)]
__global__ __launch_bounds__(256) void prep_kernel(
    const float* __restrict__ W, __bf16* __restrict__ WF)
{
  const int c = blockIdx.x * 256 + threadIdx.x;   // 8192 chunks
  const int lane_c = c & 63;
  const int ks  = (c >> 6) & 7;
  const int n0  = c >> 9;
  const int col = n0 * 16 + (lane_c & 15);
  const int k0  = ks * 32 + (lane_c >> 4) * 8;
  const float* wp = W + k0 * DD + col;
  bf16x8 fr;
  #pragma unroll
  for (int i = 0; i < 8; ++i) fr[i] = (__bf16)wp[i * DD];
  *reinterpret_cast<bf16x8*>(WF + (size_t)c * 8) = fr;
}

// Fused kernel: one 16-row strip per wave. 256 thr (4 waves)/block, 2048 blocks.
//   per wave: logits (MFMA vs L2-resident WF) -> strip softmax (m, se)
//             -> strip partial P[256] = sum_rows exp(l-m)*x  (from reg frags)
//   per block: combine the 4 wave partials via LDS -> one global partial.
// X read from HBM exactly once; no large LDS; ~56 live VGPRs -> 8 waves/SIMD.
__global__ __launch_bounds__(256, 8) void fused_kernel(
    const float* __restrict__ X, const __bf16* __restrict__ WF,
    const float* __restrict__ bias, const float* __restrict__ V,
    float* __restrict__ Pout, float* __restrict__ Mout, float* __restrict__ Sout)
{
  __shared__ float Pw[4][DD];   // 4 KB
  __shared__ float mw4[4], sw4[4];

  const int t = threadIdx.x;
  const int wave = t >> 6, lane = t & 63;
  const int g  = lane >> 4;    // k-group 0..3 (DPP row)
  const int lg = lane & 15;    // sub-lane 0..15 (= row within strip)
  const int gw = blockIdx.x * 4 + wave;            // global wave/strip id
  const size_t row = (size_t)gw * 16 + lg;
  const bf16x8* WFv = reinterpret_cast<const bf16x8*>(WF);

  // ---- Phase 1: load strip A fragments (the only HBM read of X) ----
  bf16x8 a[8];   // lane holds row lg, k = ks*32 + g*8 + i  (32 VGPRs)
  {
    const float* xr = X + row * DD;
    #pragma unroll
    for (int ks = 0; ks < 8; ++ks) {
      const float4* p = reinterpret_cast<const float4*>(xr + ks * 32 + g * 8);
      float4 f0 = p[0], f1 = p[1];
      bf16x8 fr;
      fr[0] = (__bf16)f0.x; fr[1] = (__bf16)f0.y; fr[2] = (__bf16)f0.z; fr[3] = (__bf16)f0.w;
      fr[4] = (__bf16)f1.x; fr[5] = (__bf16)f1.y; fr[6] = (__bf16)f1.z; fr[7] = (__bf16)f1.w;
      a[ks] = fr;
    }
  }

  // ---- Phase 2: 16 col-tiles; B-frags streamed from L2 ----
  float sp[4] = {0.f, 0.f, 0.f, 0.f};
  #pragma unroll 1
  for (int n0 = 0; n0 < 16; ++n0) {
    const bf16x8* bsrc = WFv + (n0 * 512 + lane);   // lane-contiguous 16B -> 1KB/instr
    f32x4 acc = {0.f, 0.f, 0.f, 0.f};
    #pragma unroll
    for (int ks = 0; ks < 8; ++ks) {
      bf16x8 bfr = bsrc[ks * 64];
      acc = __builtin_amdgcn_mfma_f32_16x16x32_bf16(a[ks], bfr, acc, 0, 0, 0);
    }
    const int col = n0 * 16 + lg;
    const float vc = V[col], bc = bias[col];        // L1-resident after first tile
    #pragma unroll
    for (int r = 0; r < 4; ++r)                     // C/D: col=lane&15, row=g*4+r
      sp[r] += fast_tanh(acc[r] + bc) * vc;
  }

  // Reduce logit partials across the 16 lg-lanes (DPP; all lanes get the sum)
  #pragma unroll
  for (int r = 0; r < 4; ++r) sp[r] = row16_sum(sp[r]);

  // Group g holds logits of rows g*4+r. Lane (g,lg) needs row lg:
  // src group = lg>>2 (any lane of it), reg r = lg&3.
  const int src = ((lg >> 2) << 4) | lg;
  float l0 = 0.f;
  #pragma unroll
  for (int r = 0; r < 4; ++r) {
    float v0 = __shfl(sp[r], src, 64);
    if ((lg & 3) == r) l0 = v0;
  }

  // ---- Phase 3: strip softmax numerators ----
  const float m  = row16_max(l0);      // strip max (l0 depends only on lg)
  const float w0 = __expf(l0 - m);
  const float se = row16_sum(w0);

  // Weighted strip partial: p8[i] covers d = ks*32+g*8+i; DPP row-reduce over rows.
  #pragma unroll
  for (int ks = 0; ks < 8; ++ks) {
    float p8[8];
    #pragma unroll
    for (int i = 0; i < 8; ++i) p8[i] = w0 * (float)a[ks][i];
    #pragma unroll
    for (int i = 0; i < 8; ++i) p8[i] = row16_sum(p8[i]);
    if (lg < 2) {
      float4 v = (lg == 0) ? make_float4(p8[0], p8[1], p8[2], p8[3])
                           : make_float4(p8[4], p8[5], p8[6], p8[7]);
      *reinterpret_cast<float4*>(&Pw[wave][ks * 32 + g * 8 + lg * 4]) = v;
    }
  }
  if (lane == 0) { mw4[wave] = m; sw4[wave] = se; }
  __syncthreads();

  // ---- Phase 4: combine 4 wave partials -> one block partial ----
  const float Mb = fmaxf(fmaxf(mw4[0], mw4[1]), fmaxf(mw4[2], mw4[3]));
  const float f0 = __expf(mw4[0] - Mb), f1 = __expf(mw4[1] - Mb);
  const float f2 = __expf(mw4[2] - Mb), f3 = __expf(mw4[3] - Mb);
  Pout[(size_t)blockIdx.x * DD + t] =
      f0 * Pw[0][t] + f1 * Pw[1][t] + f2 * Pw[2][t] + f3 * Pw[3][t];
  if (t == 0) {
    Sout[blockIdx.x] = f0 * sw4[0] + f1 * sw4[1] + f2 * sw4[2] + f3 * sw4[3];
    Mout[blockIdx.x] = Mb;
  }
}

// Combine: per batch, merge the 64 block partials with max-rescale.
__global__ __launch_bounds__(256) void combine_kernel(
    const float* __restrict__ P, const float* __restrict__ Mb,
    const float* __restrict__ Sb, float* __restrict__ ctx)
{
  const int b = blockIdx.x, t = threadIdx.x;
  const float* Mp = Mb + b * 64;
  const float* Sp = Sb + b * 64;
  float Mg = -1e30f;
  #pragma unroll 8
  for (int k = 0; k < 64; ++k) Mg = fmaxf(Mg, Mp[k]);
  float den = 0.f, acc = 0.f;
  #pragma unroll 4
  for (int k = 0; k < 64; ++k) {
    const float f = __expf(Mp[k] - Mg);
    den += f * Sp[k];
    acc += f * P[(size_t)(b * 64 + k) * DD + t];
  }
  ctx[b * DD + t] = acc / den;
}

extern "C" void kernel_launch(void* const* d_in, const int* in_sizes, int n_in,
                              void* d_out, int out_size, void* d_ws, size_t ws_size,
                              hipStream_t stream) {
  const float* X    = (const float*)d_in[0];  // [32,4096,256] fp32
  const float* W    = (const float*)d_in[1];  // [256,256]
  const float* bias = (const float*)d_in[2];  // [256]
  const float* V    = (const float*)d_in[3];  // [256,1]
  float* ctx = (float*)d_out;                 // [32,256]

  __bf16* WF = (__bf16*)d_ws;                       // 128 KB, fragment-ordered
  float* P = (float*)((char*)d_ws + 128 * 1024);    // [2048,256] = 2 MB
  float* M = P + 2048 * DD;                         // [2048]
  float* S = M + 2048;                              // [2048]

  prep_kernel<<<32, 256, 0, stream>>>(W, WF);
  fused_kernel<<<2048, 256, 0, stream>>>(X, WF, bias, V, P, M, S);
  combine_kernel<<<32, 256, 0, stream>>>(P, M, S, ctx);
}

// Round 7
// 65.134 us; speedup vs baseline: 1.2306x; 1.2306x over previous
//
#include <hip/hip_runtime.h>
#include <hip/hip_bf16.h>

#define DD 256
#define SS 4096

typedef __bf16 bf16x8 __attribute__((ext_vector_type(8)));
typedef float  f32x4  __attribute__((ext_vector_type(4)));

__device__ __forceinline__ float fast_tanh(float x) {
  float e = __expf(2.0f * x);
  return 1.0f - 2.0f / (e + 1.0f);
}

// DPP helpers: reduce across the 16-lane row (lg = lane&15) within each g-group
template<int CTRL>
__device__ __forceinline__ float dpp_mov(float v) {
  return __int_as_float(__builtin_amdgcn_update_dpp(0, __float_as_int(v), CTRL, 0xF, 0xF, true));
}
__device__ __forceinline__ float row16_sum(float v) {
  v += dpp_mov<0xB1>(v);   // quad_perm xor1
  v += dpp_mov<0x4E>(v);   // quad_perm xor2
  v += dpp_mov<0x124>(v);  // row_ror:4
  v += dpp_mov<0x128>(v);  // row_ror:8
  return v;
}
__device__ __forceinline__ float row16_max(float v) {
  v = fmaxf(v, dpp_mov<0xB1>(v));
  v = fmaxf(v, dpp_mov<0x4E>(v));
  v = fmaxf(v, dpp_mov<0x124>(v));
  v = fmaxf(v, dpp_mov<0x128>(v));
  return v;
}

// Prep: W [256,256] fp32 -> fragment-ordered bf16 WF (in d_ws).
// Chunk c = ((n0*8+ks)*64 + lane) holds 8 bf16: W[ks*32+(lane>>4)*8+i][n0*16+(lane&15)]
__global__ __launch_bounds__(256) void prep_kernel(
    const float* __restrict__ W, __bf16* __restrict__ WF)
{
  const int c = blockIdx.x * 256 + threadIdx.x;   // 8192 chunks
  const int lane_c = c & 63;
  const int ks  = (c >> 6) & 7;
  const int n0  = c >> 9;
  const int col = n0 * 16 + (lane_c & 15);
  const int k0  = ks * 32 + (lane_c >> 4) * 8;
  const float* wp = W + k0 * DD + col;
  bf16x8 fr;
  #pragma unroll
  for (int i = 0; i < 8; ++i) fr[i] = (__bf16)wp[i * DD];
  *reinterpret_cast<bf16x8*>(WF + (size_t)c * 8) = fr;
}

// Fused kernel: 256 blocks x 512 thr (8 waves). Each wave owns 64 rows
// (4 strips of 16) held as MFMA A-fragments; W-fragments in LDS (128 KB,
// staged once per block by coalesced copy of the prep output).
// Per wave: logits -> strip softmax numerators (m, se) -> weighted partial
// P[256] = sum_rows exp(l-m)*x, written straight to global. No post-GEMM
// barriers; waves are independent after staging.
__global__ __launch_bounds__(512, 2) void fused_kernel(
    const float* __restrict__ X, const __bf16* __restrict__ WF,
    const float* __restrict__ bias, const float* __restrict__ V,
    float* __restrict__ Pout, float* __restrict__ Mout, float* __restrict__ Sout)
{
  __shared__ __bf16 WtF[8192 * 8];   // 128 KB, fragment-ordered (chunk = 16B/lane)
  __shared__ float  Vs[DD];
  __shared__ float  Bs[DD];

  const int t = threadIdx.x;
  // Stage WF -> LDS, fully coalesced (prep already did the transpose/format)
  {
    const uint4* src = reinterpret_cast<const uint4*>(WF);
    uint4* dst = reinterpret_cast<uint4*>(WtF);
    #pragma unroll
    for (int i = 0; i < 16; ++i) dst[t + i * 512] = src[t + i * 512];
  }
  if (t < DD) { Vs[t] = V[t]; Bs[t] = bias[t]; }
  __syncthreads();

  const int wave = t >> 6, lane = t & 63;
  const int g  = lane >> 4;    // k-group 0..3 (DPP row)
  const int lg = lane & 15;    // sub-lane 0..15 (= row within strip)
  const int gw = blockIdx.x * 8 + wave;       // global wave id; rows [gw*64, gw*64+64)
  const size_t rowBase = (size_t)gw * 64;

  // ---- Phase 1: load 4 strips of A fragments (the only HBM read of X) ----
  bf16x8 a[4][8];   // [strip][k-step]; lane holds row st*16+lg, k = ks*32+g*8+i
  #pragma unroll
  for (int st = 0; st < 4; ++st) {
    const float* xr = X + (rowBase + st * 16 + lg) * DD;
    #pragma unroll
    for (int ks = 0; ks < 8; ++ks) {
      const float4* p = reinterpret_cast<const float4*>(xr + ks * 32 + g * 8);
      float4 f0 = p[0], f1 = p[1];
      bf16x8 fr;
      fr[0] = (__bf16)f0.x; fr[1] = (__bf16)f0.y; fr[2] = (__bf16)f0.z; fr[3] = (__bf16)f0.w;
      fr[4] = (__bf16)f1.x; fr[5] = (__bf16)f1.y; fr[6] = (__bf16)f1.z; fr[7] = (__bf16)f1.w;
      a[st][ks] = fr;
    }
  }

  // ---- Phase 2: 16 col-tiles; 8 ds_read_b128 per tile shared by 4 MFMA chains ----
  float sp[4][4] = {{0.f,0.f,0.f,0.f},{0.f,0.f,0.f,0.f},
                    {0.f,0.f,0.f,0.f},{0.f,0.f,0.f,0.f}};
  #pragma unroll 1
  for (int n0 = 0; n0 < 16; ++n0) {
    const __bf16* bp = WtF + ((size_t)(n0 * 8 * 64 + lane)) * 8;
    bf16x8 bfr[8];
    #pragma unroll
    for (int ks = 0; ks < 8; ++ks)
      bfr[ks] = *reinterpret_cast<const bf16x8*>(bp + (size_t)ks * 512);
    f32x4 acc0 = {0.f,0.f,0.f,0.f}, acc1 = {0.f,0.f,0.f,0.f};
    f32x4 acc2 = {0.f,0.f,0.f,0.f}, acc3 = {0.f,0.f,0.f,0.f};
    #pragma unroll
    for (int ks = 0; ks < 8; ++ks) {
      acc0 = __builtin_amdgcn_mfma_f32_16x16x32_bf16(a[0][ks], bfr[ks], acc0, 0, 0, 0);
      acc1 = __builtin_amdgcn_mfma_f32_16x16x32_bf16(a[1][ks], bfr[ks], acc1, 0, 0, 0);
      acc2 = __builtin_amdgcn_mfma_f32_16x16x32_bf16(a[2][ks], bfr[ks], acc2, 0, 0, 0);
      acc3 = __builtin_amdgcn_mfma_f32_16x16x32_bf16(a[3][ks], bfr[ks], acc3, 0, 0, 0);
    }
    const int col = n0 * 16 + lg;
    const float vc = Vs[col], bc = Bs[col];
    #pragma unroll
    for (int r = 0; r < 4; ++r) {          // C/D: col=lane&15, row=g*4+r
      sp[0][r] += fast_tanh(acc0[r] + bc) * vc;
      sp[1][r] += fast_tanh(acc1[r] + bc) * vc;
      sp[2][r] += fast_tanh(acc2[r] + bc) * vc;
      sp[3][r] += fast_tanh(acc3[r] + bc) * vc;
    }
  }

  // Reduce logit partials across the 16 lg-lanes (DPP; all lanes get the sum)
  #pragma unroll
  for (int st = 0; st < 4; ++st)
    #pragma unroll
    for (int r = 0; r < 4; ++r) sp[st][r] = row16_sum(sp[st][r]);

  // Group g holds logits of rows st*16 + g*4+r. Lane (g,lg) needs row lg of
  // each strip: src group = lg>>2, reg r = lg&3.
  const int src = ((lg >> 2) << 4) | lg;
  float l[4] = {0.f, 0.f, 0.f, 0.f};
  #pragma unroll
  for (int st = 0; st < 4; ++st) {
    #pragma unroll
    for (int r = 0; r < 4; ++r) {
      float v0 = __shfl(sp[st][r], src, 64);
      if ((lg & 3) == r) l[st] = v0;
    }
  }

  // ---- Phase 3: wave softmax numerators over its 64 rows ----
  float mm = fmaxf(fmaxf(l[0], l[1]), fmaxf(l[2], l[3]));
  const float m = row16_max(mm);              // l[] depend only on lg
  const float w0 = __expf(l[0] - m);
  const float w1 = __expf(l[1] - m);
  const float w2 = __expf(l[2] - m);
  const float w3 = __expf(l[3] - m);
  const float se = row16_sum((w0 + w1) + (w2 + w3));

  // Weighted partial: p8[i] covers d = ks*32+g*8+i; DPP row-reduce over rows.
  float* PoutW = Pout + (size_t)gw * DD;
  #pragma unroll
  for (int ks = 0; ks < 8; ++ks) {
    float p8[8];
    #pragma unroll
    for (int i = 0; i < 8; ++i) {
      float v = w0 * (float)a[0][ks][i];
      v = fmaf(w1, (float)a[1][ks][i], v);
      v = fmaf(w2, (float)a[2][ks][i], v);
      v = fmaf(w3, (float)a[3][ks][i], v);
      p8[i] = v;
    }
    #pragma unroll
    for (int i = 0; i < 8; ++i) p8[i] = row16_sum(p8[i]);
    if (lg < 2) {
      float4 v = (lg == 0) ? make_float4(p8[0], p8[1], p8[2], p8[3])
                           : make_float4(p8[4], p8[5], p8[6], p8[7]);
      *reinterpret_cast<float4*>(&PoutW[ks * 32 + g * 8 + lg * 4]) = v;
    }
  }
  if (lane == 0) { Mout[gw] = m; Sout[gw] = se; }
}

// Combine: per batch, merge the 64 wave partials with max-rescale.
__global__ __launch_bounds__(256) void combine_kernel(
    const float* __restrict__ P, const float* __restrict__ Mb,
    const float* __restrict__ Sb, float* __restrict__ ctx)
{
  const int b = blockIdx.x, t = threadIdx.x;
  const float* Mp = Mb + b * 64;
  const float* Sp = Sb + b * 64;
  float Mg = -1e30f;
  #pragma unroll 8
  for (int k = 0; k < 64; ++k) Mg = fmaxf(Mg, Mp[k]);
  float den = 0.f, acc = 0.f;
  #pragma unroll 4
  for (int k = 0; k < 64; ++k) {
    const float f = __expf(Mp[k] - Mg);
    den += f * Sp[k];
    acc += f * P[(size_t)(b * 64 + k) * DD + t];
  }
  ctx[b * DD + t] = acc / den;
}

extern "C" void kernel_launch(void* const* d_in, const int* in_sizes, int n_in,
                              void* d_out, int out_size, void* d_ws, size_t ws_size,
                              hipStream_t stream) {
  const float* X    = (const float*)d_in[0];  // [32,4096,256] fp32
  const float* W    = (const float*)d_in[1];  // [256,256]
  const float* bias = (const float*)d_in[2];  // [256]
  const float* V    = (const float*)d_in[3];  // [256,1]
  float* ctx = (float*)d_out;                 // [32,256]

  __bf16* WF = (__bf16*)d_ws;                       // 128 KB, fragment-ordered
  float* P = (float*)((char*)d_ws + 128 * 1024);    // [2048,256] = 2 MB
  float* M = P + 2048 * DD;                         // [2048]
  float* S = M + 2048;                              // [2048]

  prep_kernel<<<32, 256, 0, stream>>>(W, WF);
  fused_kernel<<<256, 512, 0, stream>>>(X, WF, bias, V, P, M, S);
  combine_kernel<<<32, 256, 0, stream>>>(P, M, S, ctx);
}